// Round 2
// baseline (2000.050 us; speedup 1.0000x reference)
//
#include <hip/hip_runtime.h>

// CrossAttention on MI355X (gfx950). Inputs/outputs fp32 (per reference);
// internal compute bf16 MFMA with fp32 accumulation.
// Pipeline: transpose+cast weights -> LN(latent)->bf16 -> Q GEMM ->
// per-batch-group { LN(kv)->bf16 -> K GEMM -> V GEMM (transposed store) ->
// flash attention } -> O GEMM (fp32 out).
// ws (bf16): WtQ 1M | WtK .75M | WtV .75M | WtO 1M | Aq 4M | Qbuf 4M |
// Obuf 4M | group{ Akv b*12.6M | K b*16.8M | Vt b*16.8M }, b in {8,4,2,1}
// picked from ws_size (deterministic).

typedef __bf16 bf16x8 __attribute__((ext_vector_type(8)));
typedef float f32x4 __attribute__((ext_vector_type(4)));
typedef unsigned short us4 __attribute__((ext_vector_type(4)));
typedef unsigned int u32;
typedef unsigned short u16;

#define MFMA_BF16(a, b, c) __builtin_amdgcn_mfma_f32_16x16x32_bf16(a, b, c, 0, 0, 0)

__device__ __forceinline__ u16 f2b(float f) {
    u32 x = __builtin_bit_cast(u32, f);
    x += 0x7fffu + ((x >> 16) & 1u);
    return (u16)(x >> 16);
}

// ------------- transpose+cast fp32 [R][C] -> bf16 [C][R] (weights) ----------
__global__ void transpose_f32_bf16(const float* __restrict__ in,
                                   u16* __restrict__ out, int R, int C) {
    __shared__ u16 t[32][33];
    int tx = threadIdx.x, ty = threadIdx.y;
    int bx = blockIdx.x * 32, by = blockIdx.y * 32;
#pragma unroll
    for (int j = 0; j < 4; j++)
        t[ty + j * 8][tx] = f2b(in[(long)(by + ty + j * 8) * C + bx + tx]);
    __syncthreads();
#pragma unroll
    for (int j = 0; j < 4; j++)
        out[(long)(bx + ty + j * 8) * R + by + tx] = t[tx][ty + j * 8];
}

// ------------- LayerNorm rows: fp32 in -> bf16 out, fp32 stats --------------
__global__ __launch_bounds__(256) void ln_rows(const float* __restrict__ x,
                                               const float* __restrict__ g,
                                               const float* __restrict__ bt,
                                               u16* __restrict__ y, int C) {
    long row = blockIdx.x;
    int tid = threadIdx.x;
    const float4* xf = (const float4*)(x + row * C);
    int C4 = C >> 2;
    float s = 0.f, ss = 0.f;
    for (int i = tid; i < C4; i += 256) {
        float4 v = xf[i];
        s += v.x + v.y + v.z + v.w;
        ss += v.x * v.x + v.y * v.y + v.z * v.z + v.w * v.w;
    }
#pragma unroll
    for (int off = 1; off < 64; off <<= 1) {
        s += __shfl_xor(s, off);
        ss += __shfl_xor(ss, off);
    }
    __shared__ float red[2][4];
    int wave = tid >> 6;
    if ((tid & 63) == 0) { red[0][wave] = s; red[1][wave] = ss; }
    __syncthreads();
    s = red[0][0] + red[0][1] + red[0][2] + red[0][3];
    ss = red[1][0] + red[1][1] + red[1][2] + red[1][3];
    float inv = 1.f / (float)C;
    float mu = s * inv;
    float var = ss * inv - mu * mu;
    float rstd = rsqrtf(var + 1e-5f);
    const float4* gf = (const float4*)g;
    const float4* bf_ = (const float4*)bt;
    for (int i = tid; i < C4; i += 256) {
        float4 v = xf[i], gv = gf[i], bv = bf_[i];
        us4 pk;
        pk[0] = f2b((v.x - mu) * rstd * gv.x + bv.x);
        pk[1] = f2b((v.y - mu) * rstd * gv.y + bv.y);
        pk[2] = f2b((v.z - mu) * rstd * gv.z + bv.z);
        pk[3] = f2b((v.w - mu) * rstd * gv.w + bv.w);
        *(us4*)&y[row * C + i * 4] = pk;
    }
}

// ------------- GEMM: C[M,1024] = A[M,Kd] @ Bt[1024,Kd]^T --------------------
// A, Bt are [rows][Kd] bf16 row-major (Bt = pre-transposed weight).
// VSTORE: store transposed Vt[(bl*1024+n)][key], bl=m>>14, key=m&16383.
// F32OUT: store fp32 (final output GEMM).
template <int VSTORE, int F32OUT>
__global__ __launch_bounds__(256, 2) void gemm_bt(const u16* __restrict__ A,
                                                  const u16* __restrict__ Bt,
                                                  void* __restrict__ Cv, int Kd) {
    __shared__ u16 As[128][32];
    __shared__ u16 Bs[128][32];
    int tid = threadIdx.x;
    int lane = tid & 63, wave = tid >> 6;
    int l15 = lane & 15, quad = lane >> 4;
    int wm = (wave >> 1) << 6, wn = (wave & 1) << 6;
    long m0 = (long)blockIdx.y << 7;
    int n0 = blockIdx.x << 7;
    int r0 = tid >> 2, sg = (tid & 3) << 3;
    const u16* a0 = A + (m0 + r0) * Kd + sg;
    const u16* a1 = a0 + (long)64 * Kd;
    const u16* bp0 = Bt + (long)(n0 + r0) * Kd + sg;
    const u16* bp1 = bp0 + (long)64 * Kd;
    f32x4 acc[4][4] = {};
    for (int k0 = 0; k0 < Kd; k0 += 32) {
        *(uint4*)&As[r0][sg] = *(const uint4*)(a0 + k0);
        *(uint4*)&As[r0 + 64][sg] = *(const uint4*)(a1 + k0);
        *(uint4*)&Bs[r0][sg] = *(const uint4*)(bp0 + k0);
        *(uint4*)&Bs[r0 + 64][sg] = *(const uint4*)(bp1 + k0);
        __syncthreads();
        bf16x8 af[4], bf[4];
#pragma unroll
        for (int mt = 0; mt < 4; mt++)
            af[mt] = *(const bf16x8*)&As[wm + mt * 16 + l15][quad * 8];
#pragma unroll
        for (int nt = 0; nt < 4; nt++)
            bf[nt] = *(const bf16x8*)&Bs[wn + nt * 16 + l15][quad * 8];
#pragma unroll
        for (int mt = 0; mt < 4; mt++)
#pragma unroll
            for (int nt = 0; nt < 4; nt++)
                acc[mt][nt] = MFMA_BF16(af[mt], bf[nt], acc[mt][nt]);
        __syncthreads();
    }
    // C/D layout: col = lane&15, row = quad*4 + reg
#pragma unroll
    for (int mt = 0; mt < 4; mt++) {
#pragma unroll
        for (int nt = 0; nt < 4; nt++) {
            int col = n0 + wn + nt * 16 + l15;
            long rowb = m0 + wm + mt * 16 + quad * 4;
            if constexpr (VSTORE) {
                u16* C = (u16*)Cv;
                int bl = (int)(rowb >> 14);
                int key = (int)(rowb & 16383);
                us4 pk;
#pragma unroll
                for (int r = 0; r < 4; r++) pk[r] = f2b(acc[mt][nt][r]);
                *(us4*)&C[((long)(bl * 1024 + col) << 14) + key] = pk;
            } else if constexpr (F32OUT) {
                float* C = (float*)Cv;
#pragma unroll
                for (int r = 0; r < 4; r++)
                    C[(rowb + r) * 1024 + col] = acc[mt][nt][r];
            } else {
                u16* C = (u16*)Cv;
#pragma unroll
                for (int r = 0; r < 4; r++)
                    C[(rowb + r) * 1024 + col] = f2b(acc[mt][nt][r]);
            }
        }
    }
}

// ------------- Flash attention ---------------------------------------------
// Block: one (bl, h, 128-q tile); 4 waves x 32 q; KV tiles of 64.
// S^T = mfma(Kfrag, Qfrag) -> lane holds one q column; P packed to per-wave
// LDS; PV uses pre-transposed Vt.
__global__ __launch_bounds__(256, 2) void attn_fwd(const u16* __restrict__ Qb,
                                                   const u16* __restrict__ Kb,
                                                   const u16* __restrict__ Vt,
                                                   u16* __restrict__ Ob, int b0) {
    int h = blockIdx.x & 7, bl = blockIdx.x >> 3, qblk = blockIdx.y;
    int tid = threadIdx.x, lane = tid & 63, wave = tid >> 6;
    int l15 = lane & 15, quad = lane >> 4;
    int wq = wave << 5;

    __shared__ __align__(16) char smem[54272];
    u16(*Pw)[72] = (u16(*)[72])(smem + wave * (32 * 72 * 2));
    u16(*Qs)[136] = (u16(*)[136])(smem + 18432);
    u16(*Ks)[136] = (u16(*)[136])(smem + 18432);
    u16(*Vs)[72] = (u16(*)[72])(smem + 18432 + 17408);

    long qrow0 = (long)(b0 + bl) * 512 + qblk * 128;
#pragma unroll
    for (int i = 0; i < 8; i++) {
        int L = tid + i * 256;
        int row = L >> 4, seg = L & 15;
        *(uint4*)&Qs[row][seg * 8] =
            *(const uint4*)&Qb[(qrow0 + row) * 1024 + h * 128 + seg * 8];
    }
    __syncthreads();
    bf16x8 qf[2][4];
#pragma unroll
    for (int nt = 0; nt < 2; nt++)
#pragma unroll
        for (int kc = 0; kc < 4; kc++)
            qf[nt][kc] = *(const bf16x8*)&Qs[wq + nt * 16 + l15][kc * 32 + quad * 8];
    __syncthreads();  // Q region reused for K/V below

    f32x4 o[2][8] = {};
    float m_run[2] = {-1e30f, -1e30f};
    float l_run[2] = {0.f, 0.f};
    const float scl = 0.08838834764831845f;  // 1/sqrt(128)

    const u16* Kbase = Kb + ((long)bl * 16384) * 1024 + h * 128;
    const u16* Vbase = Vt + ((long)(bl * 1024 + h * 128)) * 16384;

    for (int kv0 = 0; kv0 < 16384; kv0 += 64) {
#pragma unroll
        for (int i = 0; i < 4; i++) {
            int L = tid + i * 256;
            int row = L >> 4, seg = L & 15;
            *(uint4*)&Ks[row][seg * 8] =
                *(const uint4*)&Kbase[(long)(kv0 + row) * 1024 + seg * 8];
            int rv = L >> 3, sv = L & 7;
            *(uint4*)&Vs[rv][sv * 8] =
                *(const uint4*)&Vbase[(long)rv * 16384 + kv0 + sv * 8];
        }
        __syncthreads();

        f32x4 s[4][2] = {};
#pragma unroll
        for (int kc = 0; kc < 4; kc++) {
            bf16x8 kf[4];
#pragma unroll
            for (int mt = 0; mt < 4; mt++)
                kf[mt] = *(const bf16x8*)&Ks[mt * 16 + l15][kc * 32 + quad * 8];
#pragma unroll
            for (int mt = 0; mt < 4; mt++) {
                s[mt][0] = MFMA_BF16(kf[mt], qf[0][kc], s[mt][0]);
                s[mt][1] = MFMA_BF16(kf[mt], qf[1][kc], s[mt][1]);
            }
        }

#pragma unroll
        for (int nt = 0; nt < 2; nt++) {
            float pm = -1e30f;
#pragma unroll
            for (int mt = 0; mt < 4; mt++)
#pragma unroll
                for (int r = 0; r < 4; r++) pm = fmaxf(pm, s[mt][nt][r]);
            pm = fmaxf(pm, __shfl_xor(pm, 16));
            pm = fmaxf(pm, __shfl_xor(pm, 32));
            float mnew = fmaxf(m_run[nt], pm);
            float alpha = __expf((m_run[nt] - mnew) * scl);
            m_run[nt] = mnew;
            float mc = mnew * scl;
            float psum = 0.f;
#pragma unroll
            for (int mt = 0; mt < 4; mt++) {
                us4 pk;
#pragma unroll
                for (int r = 0; r < 4; r++) {
                    float p = __expf(s[mt][nt][r] * scl - mc);
                    psum += p;
                    pk[r] = f2b(p);
                }
                *(us4*)&Pw[nt * 16 + l15][mt * 16 + quad * 4] = pk;
            }
            psum += __shfl_xor(psum, 16);
            psum += __shfl_xor(psum, 32);
            l_run[nt] = l_run[nt] * alpha + psum;
            float af_[4];
#pragma unroll
            for (int r = 0; r < 4; r++) af_[r] = __shfl(alpha, quad * 4 + r);
#pragma unroll
            for (int n = 0; n < 8; n++)
#pragma unroll
                for (int r = 0; r < 4; r++) o[nt][n][r] *= af_[r];
        }
        __syncthreads();  // paranoia: drain P writes before PV reads

#pragma unroll
        for (int kc = 0; kc < 2; kc++) {
            bf16x8 pf0 = *(const bf16x8*)&Pw[l15][kc * 32 + quad * 8];
            bf16x8 pf1 = *(const bf16x8*)&Pw[16 + l15][kc * 32 + quad * 8];
#pragma unroll
            for (int n = 0; n < 8; n++) {
                bf16x8 vf = *(const bf16x8*)&Vs[n * 16 + l15][kc * 32 + quad * 8];
                o[0][n] = MFMA_BF16(pf0, vf, o[0][n]);
                o[1][n] = MFMA_BF16(pf1, vf, o[1][n]);
            }
        }
        __syncthreads();
    }

    long orow0 = qrow0 + wq;
#pragma unroll
    for (int nt = 0; nt < 2; nt++) {
        float lr[4];
#pragma unroll
        for (int r = 0; r < 4; r++)
            lr[r] = 1.f / __shfl(l_run[nt], quad * 4 + r);
#pragma unroll
        for (int n = 0; n < 8; n++) {
            int col = h * 128 + n * 16 + l15;
#pragma unroll
            for (int r = 0; r < 4; r++)
                Ob[(orow0 + nt * 16 + quad * 4 + r) * 1024 + col] =
                    f2b(o[nt][n][r] * lr[r]);
        }
    }
}

// ---------------------------------------------------------------------------
extern "C" void kernel_launch(void* const* d_in, const int* in_sizes, int n_in,
                              void* d_out, int out_size, void* d_ws, size_t ws_size,
                              hipStream_t stream) {
    const float* latent = (const float*)d_in[0];
    const float* inpkv = (const float*)d_in[1];
    const float* W_Q = (const float*)d_in[2];
    const float* W_K = (const float*)d_in[3];
    const float* W_V = (const float*)d_in[4];
    const float* W_O = (const float*)d_in[5];
    const float* g_lat = (const float*)d_in[6];
    const float* b_lat = (const float*)d_in[7];
    const float* g_in = (const float*)d_in[8];
    const float* b_in = (const float*)d_in[9];
    float* out = (float*)d_out;

    u16* ws = (u16*)d_ws;
    u16* WtQ = ws;  ws += 1024L * 1024;
    u16* WtK = ws;  ws += 1024L * 768;
    u16* WtV = ws;  ws += 1024L * 768;
    u16* WtO = ws;  ws += 1024L * 1024;
    u16* Aq = ws;   ws += 4096L * 1024;
    u16* Qbuf = ws; ws += 4096L * 1024;
    u16* Obuf = ws; ws += 4096L * 1024;
    size_t fixed_bytes = (size_t)((char*)ws - (char*)d_ws);
    size_t per_batch = (size_t)(16384L * 768 + 2 * 16384L * 1024) * 2;
    int bstep = 1;
    for (int b = 8; b >= 1; b >>= 1)
        if (ws_size >= fixed_bytes + (size_t)b * per_batch) { bstep = b; break; }
    u16* Akv = ws;
    u16* Kbf = Akv + (long)bstep * 16384 * 768;
    u16* Vtb = Kbf + (long)bstep * 16384 * 1024;

    dim3 t328(32, 8);
    transpose_f32_bf16<<<dim3(32, 32), t328, 0, stream>>>(W_Q, WtQ, 1024, 1024);
    transpose_f32_bf16<<<dim3(32, 24), t328, 0, stream>>>(W_K, WtK, 768, 1024);
    transpose_f32_bf16<<<dim3(32, 24), t328, 0, stream>>>(W_V, WtV, 768, 1024);
    transpose_f32_bf16<<<dim3(32, 32), t328, 0, stream>>>(W_O, WtO, 1024, 1024);

    ln_rows<<<4096, 256, 0, stream>>>(latent, g_lat, b_lat, Aq, 1024);
    gemm_bt<0, 0><<<dim3(8, 32), 256, 0, stream>>>(Aq, WtQ, Qbuf, 1024);

    for (int b0 = 0; b0 < 8; b0 += bstep) {
        ln_rows<<<bstep * 16384, 256, 0, stream>>>(inpkv + (long)b0 * 16384 * 768,
                                                   g_in, b_in, Akv, 768);
        gemm_bt<0, 0><<<dim3(8, bstep * 128), 256, 0, stream>>>(Akv, WtK, Kbf, 768);
        gemm_bt<1, 0><<<dim3(8, bstep * 128), 256, 0, stream>>>(Akv, WtV, Vtb, 768);
        attn_fwd<<<dim3(bstep * 8, 4), 256, 0, stream>>>(Qbuf, Kbf, Vtb, Obuf, b0);
    }
    gemm_bt<0, 1><<<dim3(8, 32), 256, 0, stream>>>(Obuf, WtO, out, 1024);
}